// Round 7
// baseline (7154.151 us; speedup 1.0000x reference)
//
#include <hip/hip_runtime.h>

// ---------------- problem constants ----------------
#define VV 50000
#define EE 512
#define HH 256
#define BB 32
#define SS 1024
#define G4 1024   // 4*H

typedef __attribute__((ext_vector_type(8))) short short8;
typedef __attribute__((ext_vector_type(4))) float float4v;
typedef __attribute__((ext_vector_type(2))) float float2v;
typedef __attribute__((ext_vector_type(4))) unsigned short ushort4v;
typedef __attribute__((ext_vector_type(4))) unsigned int uint4v;

#define MFMA(a, b, c) __builtin_amdgcn_mfma_f32_16x16x32_bf16(a, b, c, 0, 0, 0)

__device__ __forceinline__ float b2f(unsigned short u) {
  union { unsigned int i; float f; } v; v.i = ((unsigned int)u) << 16; return v.f;
}
__device__ __forceinline__ unsigned short f2b(float f) {
  union { float f; unsigned int i; } v; v.f = f;
  unsigned int u = v.i;
  return (unsigned short)((u + 0x7fffu + ((u >> 16) & 1u)) >> 16);
}
// pack 8 consecutive fp32 (16B-aligned) -> short8 of bf16
__device__ __forceinline__ short8 pack8(const float* p) {
  float4v x0 = *(const float4v*)p;
  float4v x1 = *(const float4v*)(p + 4);
  short8 r;
  r[0] = (short)f2b(x0[0]); r[1] = (short)f2b(x0[1]);
  r[2] = (short)f2b(x0[2]); r[3] = (short)f2b(x0[3]);
  r[4] = (short)f2b(x1[0]); r[5] = (short)f2b(x1[1]);
  r[6] = (short)f2b(x1[2]); r[7] = (short)f2b(x1[3]);
  return r;
}
__device__ __forceinline__ float sigm(float x) {
  return __builtin_amdgcn_rcpf(1.0f + __expf(-x));
}
__device__ __forceinline__ float tanh_f(float x) {
  return 1.0f - 2.0f * __builtin_amdgcn_rcpf(__expf(2.0f * x) + 1.0f);
}

// ---------------- kernel 1: fmask scan -> order/counts ----------------
__global__ __launch_bounds__(256) void k_scan(const int* __restrict__ fmask,
                                              int* __restrict__ order,
                                              int* __restrict__ counts) {
  __shared__ int sh[256];
  const int b = blockIdx.x;
  const int tid = threadIdx.x;
  int m0[4];
  const int base = b * SS + tid * 4;
#pragma unroll
  for (int j = 0; j < 4; ++j) m0[j] = fmask[base + j];
  const int s = m0[0] + m0[1] + m0[2] + m0[3];
  sh[tid] = s;
  __syncthreads();
  for (int off = 1; off < 256; off <<= 1) {
    int v = 0;
    if (tid >= off) v = sh[tid - off];
    __syncthreads();
    sh[tid] += v;
    __syncthreads();
  }
  const int incl = sh[tid];
  int pos = incl - s;
#pragma unroll
  for (int j = 0; j < 4; ++j) {
    if (m0[j]) order[b * SS + pos++] = tid * 4 + j;
  }
  if (tid == 255) counts[b] = incl;
}

// ---------------- kernel 2: embedding-gather + input GEMM ----------------
// xg[d][t][b][gate] (bf16), computed as C^T via swapped MFMA operands.
#define BM 128
#define BN 128
#define BK 32
#define LSTR 56

__global__ __launch_bounds__(256, 2) void k_gemm(
    const int* __restrict__ inputs, const int* __restrict__ seqlen,
    const float* __restrict__ emb,
    const float* __restrict__ Wih_f, const float* __restrict__ Wih_b,
    const float* __restrict__ bih_f, const float* __restrict__ bih_b,
    const float* __restrict__ bhh_f, const float* __restrict__ bhh_b,
    unsigned short* __restrict__ xg) {
  __shared__ short As[BM * LSTR];
  __shared__ short Bs[BN * LSTR];
  __shared__ int tokL[BM];

  const int d = blockIdx.y;
  const int mt = blockIdx.x >> 3, nt = blockIdx.x & 7;
  const int Mbase = mt * BM, Nbase = nt * BN;
  const int tid = threadIdx.x;
  const float* Wih = d ? Wih_b : Wih_f;

  if (tid < BM) {
    const int m = Mbase + tid;
    const int t = m >> 5, b = m & 31;
    int tok;
    if (d == 0) {
      tok = inputs[b * SS + t];
    } else {
      const int L = seqlen[b];
      tok = (t < L) ? inputs[b * SS + (L - 1 - t)] : 0;
    }
    tokL[tid] = tok;
  }
  __syncthreads();

  const int wave = tid >> 6, lane = tid & 63, ln = lane & 15, q = lane >> 4;
  const int wm = wave & 1, wn = wave >> 1;

  float4v acc[4][4];   // [ni (gate tile)][mi (txb tile)]
#pragma unroll
  for (int ni = 0; ni < 4; ++ni)
#pragma unroll
    for (int mi = 0; mi < 4; ++mi) acc[ni][mi] = (float4v){0.f, 0.f, 0.f, 0.f};

  for (int kb = 0; kb < (EE / BK); ++kb) {
    const int k0 = kb * BK;
    if (kb) __syncthreads();
#pragma unroll
    for (int i = 0; i < 2; ++i) {
      const int c = tid + i * 256;
      const int row = c >> 2, sub = c & 3;
      const short8 av = pack8(emb + (size_t)tokL[row] * EE + k0 + sub * 8);
      *(short8*)(As + row * LSTR + sub * 8) = av;
      const short8 bv = pack8(Wih + (size_t)(Nbase + row) * EE + k0 + sub * 8);
      *(short8*)(Bs + row * LSTR + sub * 8) = bv;
    }
    __syncthreads();
    short8 af[4], bfr[4];
#pragma unroll
    for (int mi = 0; mi < 4; ++mi)
      af[mi] = *(const short8*)(As + (wm * 64 + mi * 16 + ln) * LSTR + q * 8);
#pragma unroll
    for (int ni = 0; ni < 4; ++ni)
      bfr[ni] = *(const short8*)(Bs + (wn * 64 + ni * 16 + ln) * LSTR + q * 8);
#pragma unroll
    for (int ni = 0; ni < 4; ++ni)
#pragma unroll
      for (int mi = 0; mi < 4; ++mi)
        acc[ni][mi] = MFMA(bfr[ni], af[mi], acc[ni][mi]);   // swapped operands
  }

  const float* bih = d ? bih_b : bih_f;
  const float* bhh = d ? bhh_b : bhh_f;
  float biasv[4][4];
#pragma unroll
  for (int ni = 0; ni < 4; ++ni)
#pragma unroll
    for (int r = 0; r < 4; ++r) {
      const int col = Nbase + wn * 64 + ni * 16 + q * 4 + r;
      biasv[ni][r] = bih[col] + bhh[col];
    }
#pragma unroll
  for (int ni = 0; ni < 4; ++ni) {
    const int gate0 = Nbase + wn * 64 + ni * 16 + q * 4;
#pragma unroll
    for (int mi = 0; mi < 4; ++mi) {
      const int m = Mbase + wm * 64 + mi * 16 + ln;
      const int t = m >> 5, b0 = m & 31;
      ushort4v pk;
#pragma unroll
      for (int r = 0; r < 4; ++r) pk[r] = f2b(acc[ni][mi][r] + biasv[ni][r]);
      *(ushort4v*)(xg + (((size_t)d * SS + t) * BB + b0) * G4 + gate0) = pk;
    }
  }
}

// ---------------- kernel 3: recurrence (pairwise unit-split, 2 blocks/dir) ----------------
// r0-r6 post-mortem: with 8-way all-to-all, per-step sync latency pinned at
// 4.5-7k cy across four protocols; compute only ~900cy. Restructure: TWO
// 512-thread blocks per direction, each holding HALF of W_hh in VGPRs
// (128/lane, 8 waves). Own-half h is exchanged via LDS (XOR-swizzled,
// conflict-free; lgkmcnt-only barrier). Only the FOREIGN half crosses
// blocks, via the r4/r6-proven same-XCD L2 substrate: plain 8B stores +
// batched dwordx4 'sc0 nt' sentinel polls. 'nt' is the correctness-carrying
// flag (r1/r5 hung without it: the polled line parks in L1 and retries read
// the stale sentinel forever). Latency hiding: issue the 8 foreign loads
// FIRST (no wait), run the own-half LDS-MFMAs while they fly, then a
// register-passthrough vmcnt(0) + sentinel check. Per-CU compute is 4x r6
// (8 h/lane) so VALU, not sync, should set the step. Probe+vote engages L2
// mode only if the pair sees each other through L2; else MALL fallback
// (agent atomics, correct under any placement). Sentinel: hbuf pre-poisoned
// 0x7f7f (bf16 3.4e38, unreachable since |h|<=1; 8B stores don't tear).
// t=0 skips the h-GEMM (h_0 = 0). Weight frags stored order-local
// (kt_g = i ^ (j<<2)) so all steady-loop register indices are compile-time.
#define SENTQ 0x7f7f7f7f7f7f7f7full
#define PMAGIC 0x51A600

__device__ __forceinline__ int l2probe(const int* p) {
  int v;
  asm volatile("global_load_dword %0, %1, off sc0 nt\n\t"
               "s_waitcnt vmcnt(0)"
               : "=v"(v) : "v"(p) : "memory");
  return v;
}

// issue 8 foreign fragment loads (2 row bases x 4 kt), NO wait
__device__ __forceinline__ void l2pair_issue(const void* p0, const void* p1,
                                             uint4v* r) {
  asm volatile(
      "global_load_dwordx4 %0, %8, off sc0 nt\n\t"
      "global_load_dwordx4 %1, %8, off offset:64 sc0 nt\n\t"
      "global_load_dwordx4 %2, %8, off offset:128 sc0 nt\n\t"
      "global_load_dwordx4 %3, %8, off offset:192 sc0 nt\n\t"
      "global_load_dwordx4 %4, %9, off sc0 nt\n\t"
      "global_load_dwordx4 %5, %9, off offset:64 sc0 nt\n\t"
      "global_load_dwordx4 %6, %9, off offset:128 sc0 nt\n\t"
      "global_load_dwordx4 %7, %9, off offset:192 sc0 nt\n\t"
      : "=&v"(r[0]), "=&v"(r[1]), "=&v"(r[2]), "=&v"(r[3]),
        "=&v"(r[4]), "=&v"(r[5]), "=&v"(r[6]), "=&v"(r[7])
      : "v"(p0), "v"(p1)
      : "memory");
}
// same but with wait (retry path)
__device__ __forceinline__ void l2pair(const void* p0, const void* p1,
                                       uint4v* r) {
  asm volatile(
      "global_load_dwordx4 %0, %8, off sc0 nt\n\t"
      "global_load_dwordx4 %1, %8, off offset:64 sc0 nt\n\t"
      "global_load_dwordx4 %2, %8, off offset:128 sc0 nt\n\t"
      "global_load_dwordx4 %3, %8, off offset:192 sc0 nt\n\t"
      "global_load_dwordx4 %4, %9, off sc0 nt\n\t"
      "global_load_dwordx4 %5, %9, off offset:64 sc0 nt\n\t"
      "global_load_dwordx4 %6, %9, off offset:128 sc0 nt\n\t"
      "global_load_dwordx4 %7, %9, off offset:192 sc0 nt\n\t"
      "s_waitcnt vmcnt(0)"
      : "=&v"(r[0]), "=&v"(r[1]), "=&v"(r[2]), "=&v"(r[3]),
        "=&v"(r[4]), "=&v"(r[5]), "=&v"(r[6]), "=&v"(r[7])
      : "v"(p0), "v"(p1)
      : "memory");
}
// wait with register pass-through: pins consumers AFTER the wait (rule #18)
__device__ __forceinline__ void vwait8(uint4v* r) {
  asm volatile("s_waitcnt vmcnt(0)"
               : "+v"(r[0]), "+v"(r[1]), "+v"(r[2]), "+v"(r[3]),
                 "+v"(r[4]), "+v"(r[5]), "+v"(r[6]), "+v"(r[7])
               :: "memory");
}

__global__ __launch_bounds__(512, 2) void k_recur(
    const float* __restrict__ Whh_f, const float* __restrict__ Whh_b,
    const unsigned short* __restrict__ xg, unsigned short* __restrict__ hbuf,
    int* __restrict__ proto) {
  __shared__ unsigned short lh[2][BB][128];   // own-half h, XOR-swizzled
  __shared__ int s_mode;

  const int beta = blockIdx.x;
  const int xcd = beta & 7, j = beta >> 3;    // j = unit-half; partner = beta^8
  if (xcd >= 2) return;
  const int d = xcd;
  const float* Whh = d ? Whh_b : Whh_f;
  const int tid = threadIdx.x;
  const int lane = tid & 63, ln = lane & 15, q = lane >> 4;
  const int wv = tid >> 6;                    // wave 0..7

  // ---- init: pairwise coherence probe + MALL-vote ----
  if (tid == 0) {
    int* probes = proto;          // 4 ints
    int* vote_ok = proto + 8;     // 2 ints
    int* vote_n = proto + 10;     // 2 ints
    probes[d * 2 + j] = PMAGIC + d * 2 + j;   // plain store (= h store type)
    int ok = 0;
    for (int it = 0; it < 512 && !ok; ++it) {
      ok = (l2probe(probes + d * 2 + 0) == PMAGIC + d * 2 + 0) &
           (l2probe(probes + d * 2 + 1) == PMAGIC + d * 2 + 1);
    }
    __hip_atomic_fetch_add(vote_ok + d, ok, __ATOMIC_RELAXED,
                           __HIP_MEMORY_SCOPE_AGENT);
    __hip_atomic_fetch_add(vote_n + d, 1, __ATOMIC_RELEASE,
                           __HIP_MEMORY_SCOPE_AGENT);
    while (__hip_atomic_load(vote_n + d, __ATOMIC_ACQUIRE,
                             __HIP_MEMORY_SCOPE_AGENT) < 2) {}
    s_mode = (__hip_atomic_load(vote_ok + d, __ATOMIC_RELAXED,
                                __HIP_MEMORY_SCOPE_AGENT) == 2);
  }
  __syncthreads();
  const int mode_l2 = s_mode;

  // weights: order-local fragments. w[G][i]: global kt = i ^ (j<<2);
  // i<4 = own half, i>=4 = foreign half. All loop indices compile-time.
  short8 w[4][8];
#pragma unroll
  for (int G = 0; G < 4; ++G) {
    const int grow = G * 256 + j * 128 + wv * 16 + ln;
#pragma unroll
    for (int i = 0; i < 8; ++i) {
      const int kt_g = i ^ (j << 2);
      w[G][i] = pack8(Whh + (size_t)grow * HH + kt_g * 32 + q * 8);
    }
  }

  float c4[2][4] = {{0.f, 0.f, 0.f, 0.f}, {0.f, 0.f, 0.f, 0.f}};
  unsigned short* hb = hbuf + (size_t)d * 1025 * BB * HH;
  const unsigned short* xgd = xg + (size_t)d * SS * BB * G4;
  const int uoff = j * 128 + wv * 16 + q * 4;        // own unit base (shorts)
  const int foff = (1 - j) * 128 + q * 8;            // foreign kk base (shorts)
  const int lws = ((wv * 16 + q * 4) * 2) ^ ((ln & 7) << 4);  // swz LDS write

  // xg for t=0 (two static buffers, roles swap per parity -> no runtime idx)
  ushort4v xga[4][2], xgb[4][2];
#pragma unroll
  for (int G = 0; G < 4; ++G)
#pragma unroll
    for (int ct = 0; ct < 2; ++ct)
      xga[G][ct] = *(const ushort4v*)(xgd + ((size_t)0 * BB + ct * 16 + ln) * G4 +
                                      G * 256 + uoff);

#define STEP_FAST(T_, XC, XN)                                                  \
  {                                                                            \
    const int t_ = (T_);                                                       \
    float4v acc[4][2];                                                         \
    _Pragma("unroll") for (int G = 0; G < 4; ++G)                              \
        _Pragma("unroll") for (int ct = 0; ct < 2; ++ct)                       \
            acc[G][ct] = (float4v){0.f, 0.f, 0.f, 0.f};                        \
    uint4v f_[8];                                                              \
    const unsigned short* fb0 = hb + ((size_t)t_ * BB + ln) * HH + foff;       \
    const unsigned short* fb1 = hb + ((size_t)t_ * BB + 16 + ln) * HH + foff;  \
    if (t_ > 0) {                                                              \
      l2pair_issue(fb0, fb1, f_); /* foreign flies under own compute */        \
      _Pragma("unroll") for (int ct = 0; ct < 2; ++ct) {                       \
        const char* rb = (const char*)&lh[t_ & 1][ct * 16 + ln][0];            \
        _Pragma("unroll") for (int ktl = 0; ktl < 4; ++ktl) {                  \
          const int rs = (ktl * 64 + q * 16) ^ ((ln & 7) << 4);                \
          const short8 fr = *(const short8*)(rb + rs);                         \
          _Pragma("unroll") for (int G = 0; G < 4; ++G)                        \
              acc[G][ct] = MFMA(w[G][ktl], fr, acc[G][ct]);                    \
        }                                                                      \
      }                                                                        \
      vwait8(f_);                                                              \
      __builtin_amdgcn_sched_barrier(0);                                       \
      for (;;) {                                                               \
        bool bad = false;                                                      \
        _Pragma("unroll") for (int i = 0; i < 8; ++i) {                        \
          union { uint4v v; unsigned long long qq[2]; } u;                     \
          u.v = f_[i];                                                         \
          bad |= (u.qq[0] == SENTQ) | (u.qq[1] == SENTQ);                      \
        }                                                                      \
        if (!bad) break;                                                       \
        l2pair(fb0, fb1, f_);                                                  \
        __builtin_amdgcn_sched_barrier(0);                                     \
      }                                                                        \
      _Pragma("unroll") for (int ktl = 0; ktl < 4; ++ktl) {                    \
        union { uint4v v; short8 s8; } u0, u1;                                 \
        u0.v = f_[ktl]; u1.v = f_[4 + ktl];                                    \
        _Pragma("unroll") for (int G = 0; G < 4; ++G) {                        \
          acc[G][0] = MFMA(w[G][4 + ktl], u0.s8, acc[G][0]);                   \
          acc[G][1] = MFMA(w[G][4 + ktl], u1.s8, acc[G][1]);                   \
        }                                                                      \
      }                                                                        \
    }                                                                          \
    if (t_ + 1 < SS) { /* prefetch at the natural vmcnt==0 point (r6) */       \
      _Pragma("unroll") for (int G = 0; G < 4; ++G)                            \
          _Pragma("unroll") for (int ct = 0; ct < 2; ++ct)                     \
              XN[G][ct] = *(const ushort4v*)(xgd +                             \
                  ((size_t)(t_ + 1) * BB + ct * 16 + ln) * G4 + G * 256 +      \
                  uoff);                                                       \
    }                                                                          \
    _Pragma("unroll") for (int ct = 0; ct < 2; ++ct) {                         \
      unsigned long long pv = 0ull;                                            \
      _Pragma("unroll") for (int r = 0; r < 4; ++r) {                          \
        const float gi = acc[0][ct][r] + b2f(XC[0][ct][r]);                    \
        const float gf = acc[1][ct][r] + b2f(XC[1][ct][r]);                    \
        const float gg = acc[2][ct][r] + b2f(XC[2][ct][r]);                    \
        const float go = acc[3][ct][r] + b2f(XC[3][ct][r]);                    \
        const float cn = sigm(gf) * c4[ct][r] + sigm(gi) * tanh_f(gg);         \
        c4[ct][r] = cn;                                                        \
        const float h = sigm(go) * tanh_f(cn);                                 \
        pv |= ((unsigned long long)f2b(h)) << (16 * r);                        \
      }                                                                        \
      *(unsigned long long*)(hb + ((size_t)(t_ + 1) * BB + ct * 16 + ln) * HH +\
                             uoff) = pv; /* plain: partner polls sc0 nt */     \
      *(unsigned long long*)((char*)&lh[(t_ + 1) & 1][ct * 16 + ln][0] +       \
                             lws) = pv;                                        \
    }                                                                          \
    __builtin_amdgcn_sched_barrier(0);                                         \
    asm volatile("s_waitcnt lgkmcnt(0)" ::: "memory");                         \
    __builtin_amdgcn_s_barrier();                                              \
    __builtin_amdgcn_sched_barrier(0);                                         \
  }

  if (mode_l2) {
    for (int t0 = 0; t0 < SS; t0 += 2) {
      STEP_FAST(t0, xga, xgb);
      STEP_FAST(t0 + 1, xgb, xga);
    }
  } else {
    // ---------- MALL fallback: same split, agent-scope foreign ----------
    ushort4v xc[4][2], xn[4][2];
#pragma unroll
    for (int G = 0; G < 4; ++G)
#pragma unroll
      for (int ct = 0; ct < 2; ++ct) xc[G][ct] = xga[G][ct];
    for (int t = 0; t < SS; ++t) {
      if (t + 1 < SS) {
#pragma unroll
        for (int G = 0; G < 4; ++G)
#pragma unroll
          for (int ct = 0; ct < 2; ++ct)
            xn[G][ct] = *(const ushort4v*)(xgd +
                ((size_t)(t + 1) * BB + ct * 16 + ln) * G4 + G * 256 + uoff);
      }
      float4v acc[4][2];
#pragma unroll
      for (int G = 0; G < 4; ++G)
#pragma unroll
        for (int ct = 0; ct < 2; ++ct) acc[G][ct] = (float4v){0.f, 0.f, 0.f, 0.f};
      if (t > 0) {
#pragma unroll
        for (int ct = 0; ct < 2; ++ct) {
          const char* rb = (const char*)&lh[t & 1][ct * 16 + ln][0];
#pragma unroll
          for (int ktl = 0; ktl < 4; ++ktl) {
            const int rs = (ktl * 64 + q * 16) ^ ((ln & 7) << 4);
            const short8 fr = *(const short8*)(rb + rs);
#pragma unroll
            for (int G = 0; G < 4; ++G) acc[G][ct] = MFMA(w[G][ktl], fr, acc[G][ct]);
          }
        }
        unsigned long long fq0[8], fq1[8];
        const unsigned long long* b0 =
            (const unsigned long long*)(hb + ((size_t)t * BB + ln) * HH + foff);
        const unsigned long long* b1 =
            (const unsigned long long*)(hb + ((size_t)t * BB + 16 + ln) * HH + foff);
        for (;;) {
#pragma unroll
          for (int i = 0; i < 8; ++i) {
            fq0[i] = __hip_atomic_load(b0 + (i >> 1) * 8 + (i & 1),
                                       __ATOMIC_RELAXED, __HIP_MEMORY_SCOPE_AGENT);
            fq1[i] = __hip_atomic_load(b1 + (i >> 1) * 8 + (i & 1),
                                       __ATOMIC_RELAXED, __HIP_MEMORY_SCOPE_AGENT);
          }
          bool bad = false;
#pragma unroll
          for (int i = 0; i < 8; ++i) bad |= (fq0[i] == SENTQ) | (fq1[i] == SENTQ);
          if (!bad) break;
          __builtin_amdgcn_s_sleep(1);
        }
#pragma unroll
        for (int ktl = 0; ktl < 4; ++ktl) {
          union { unsigned long long u[2]; short8 s; } h0, h1;
          h0.u[0] = fq0[ktl * 2]; h0.u[1] = fq0[ktl * 2 + 1];
          h1.u[0] = fq1[ktl * 2]; h1.u[1] = fq1[ktl * 2 + 1];
#pragma unroll
          for (int G = 0; G < 4; ++G) {
            acc[G][0] = MFMA(w[G][4 + ktl], h0.s, acc[G][0]);
            acc[G][1] = MFMA(w[G][4 + ktl], h1.s, acc[G][1]);
          }
        }
      }
#pragma unroll
      for (int ct = 0; ct < 2; ++ct) {
        unsigned long long pv = 0ull;
#pragma unroll
        for (int r = 0; r < 4; ++r) {
          const float gi = acc[0][ct][r] + b2f(xc[0][ct][r]);
          const float gf = acc[1][ct][r] + b2f(xc[1][ct][r]);
          const float gg = acc[2][ct][r] + b2f(xc[2][ct][r]);
          const float go = acc[3][ct][r] + b2f(xc[3][ct][r]);
          const float cn = sigm(gf) * c4[ct][r] + sigm(gi) * tanh_f(gg);
          c4[ct][r] = cn;
          const float h = sigm(go) * tanh_f(cn);
          pv |= ((unsigned long long)f2b(h)) << (16 * r);
        }
        __hip_atomic_store(
            (unsigned long long*)(hb + ((size_t)(t + 1) * BB + ct * 16 + ln) * HH +
                                  uoff),
            pv, __ATOMIC_RELAXED, __HIP_MEMORY_SCOPE_AGENT);
        *(unsigned long long*)((char*)&lh[(t + 1) & 1][ct * 16 + ln][0] + lws) = pv;
      }
      __builtin_amdgcn_sched_barrier(0);
      asm volatile("s_waitcnt lgkmcnt(0)" ::: "memory");
      __builtin_amdgcn_s_barrier();
      __builtin_amdgcn_sched_barrier(0);
#pragma unroll
      for (int G = 0; G < 4; ++G)
#pragma unroll
        for (int ct = 0; ct < 2; ++ct) xc[G][ct] = xn[G][ct];
    }
  }
#undef STEP_FAST
}

// ---------------- kernel 4: masked compaction gather -> out (fp32) ----------------
__global__ __launch_bounds__(256) void k_gather(
    const unsigned short* __restrict__ hbuf, const int* __restrict__ order,
    const int* __restrict__ counts, float* __restrict__ out) {
  const int bj = blockIdx.x;            // (b, j)
  const int b = bj >> 10, j = bj & 1023;
  const int tid = threadIdx.x;
  const int cnt = counts[b];
  float2v val = (float2v){0.f, 0.f};
  if (j < cnt) {
    const int half = tid >> 7;          // 0: forward, 1: backward
    const int e2 = (tid & 127) * 2;
    const int tsel = half ? order[b * SS + (cnt - 1 - j)] : order[b * SS + j];
    const unsigned short* src =
        hbuf + (((size_t)half * 1025 + (tsel + 1)) * BB + b) * HH + e2;
    const unsigned int u = *(const unsigned int*)src;
    val[0] = b2f((unsigned short)u);
    val[1] = b2f((unsigned short)(u >> 16));
  }
  *(float2v*)(out + (size_t)bj * 512 + tid * 2) = val;
}

// ---------------- host ----------------
extern "C" void kernel_launch(void* const* d_in, const int* in_sizes, int n_in,
                              void* d_out, int out_size, void* d_ws, size_t ws_size,
                              hipStream_t stream) {
  (void)in_sizes; (void)n_in; (void)out_size; (void)ws_size;
  const int* inputs = (const int*)d_in[0];
  const int* seqlen = (const int*)d_in[1];
  const int* fmask  = (const int*)d_in[2];
  const float* emb  = (const float*)d_in[5];
  const float* fWih = (const float*)d_in[6];
  const float* fWhh = (const float*)d_in[7];
  const float* fbih = (const float*)d_in[8];
  const float* fbhh = (const float*)d_in[9];
  const float* bWih = (const float*)d_in[10];
  const float* bWhh = (const float*)d_in[11];
  const float* bbih = (const float*)d_in[12];
  const float* bbhh = (const float*)d_in[13];
  float* out = (float*)d_out;

  char* ws = (char*)d_ws;
  int* proto  = (int*)(ws + 0);                 // 4 probes + 2 vote_ok + 2 vote_n
  int* counts = (int*)(ws + 12800);             // 32 ints
  int* order  = (int*)(ws + 16384);             // 32*1024 ints
  const size_t o_hbuf = (size_t)1 << 18;
  unsigned short* hbuf = (unsigned short*)(ws + o_hbuf);          // 2*1025*32*256 bf16
  const size_t hbuf_bytes = (size_t)2 * 1025 * BB * HH * 2;       // 33,587,200
  const size_t o_xg = o_hbuf + hbuf_bytes;
  unsigned short* xg = (unsigned short*)(ws + o_xg);              // 2*1024*32*1024 bf16

  hipMemsetAsync(proto, 0, 128, stream);
  // poison hbuf with the sentinel pattern (bf16 0x7f7f = 3.4e38, a value the
  // recurrence can never produce); slot 0 is never read (t=0 skips the GEMM).
  hipMemsetAsync(hbuf, 0x7f, hbuf_bytes, stream);

  k_scan<<<32, 256, 0, stream>>>(fmask, order, counts);
  k_gemm<<<dim3(2048, 2), 256, 0, stream>>>(inputs, seqlen, emb, fWih, bWih,
                                            fbih, bbih, fbhh, bbhh, xg);
  k_recur<<<16, 512, 0, stream>>>(fWhh, bWhh, xg, hbuf, proto);
  k_gather<<<BB * SS, 256, 0, stream>>>(hbuf, order, counts, out);
}